// Round 1
// baseline (665.074 us; speedup 1.0000x reference)
//
#include <hip/hip_runtime.h>
#include <hip/hip_bf16.h>

// ---------------------------------------------------------------------------
// CapsNet forward: conv(3->8)+relu+pool, conv(8->16)+relu+pool,
// conv(16->32)+relu+pool, routing1 (R=64,C=32 -> N=32,O=8),
// routing2 (R=32,C=8 -> N=15,O=16) + FC(240->15).
// fp32 throughout. B=512.
// ---------------------------------------------------------------------------

// Fused 3x3 SAME conv + ReLU + 2x2 maxpool. One thread per pooled output.
template<int CIN, int COUT, int HIN>
__global__ __launch_bounds__(256)
void conv_relu_pool(const float* __restrict__ in, const float* __restrict__ w,
                    const float* __restrict__ bias, float* __restrict__ out, int B)
{
    constexpr int HOUT = HIN / 2;
    __shared__ float wl[COUT * CIN * 9];
    __shared__ float bl[COUT];
    for (int i = threadIdx.x; i < COUT * CIN * 9; i += blockDim.x) wl[i] = w[i];
    if (threadIdx.x < COUT) bl[threadIdx.x] = bias[threadIdx.x];
    __syncthreads();

    int idx = blockIdx.x * blockDim.x + threadIdx.x;
    int total = B * COUT * HOUT * HOUT;
    if (idx >= total) return;

    int px = idx % HOUT;
    int py = (idx / HOUT) % HOUT;
    int o  = (idx / (HOUT * HOUT)) % COUT;
    int b  = idx / (HOUT * HOUT * COUT);

    float a00 = 0.f, a01 = 0.f, a10 = 0.f, a11 = 0.f;
    int y0 = 2 * py - 1, x0 = 2 * px - 1;

    for (int c = 0; c < CIN; ++c) {
        float patch[4][4];
        const float* ip = in + ((size_t)b * CIN + c) * HIN * HIN;
#pragma unroll
        for (int iy = 0; iy < 4; ++iy) {
            int y = y0 + iy;
#pragma unroll
            for (int ix = 0; ix < 4; ++ix) {
                int x = x0 + ix;
                patch[iy][ix] = (y >= 0 && y < HIN && x >= 0 && x < HIN)
                                    ? ip[y * HIN + x] : 0.f;
            }
        }
        const float* wp = wl + (o * CIN + c) * 9;
#pragma unroll
        for (int ky = 0; ky < 3; ++ky)
#pragma unroll
            for (int kx = 0; kx < 3; ++kx) {
                float wv = wp[ky * 3 + kx];
                a00 = fmaf(patch[0 + ky][0 + kx], wv, a00);
                a01 = fmaf(patch[0 + ky][1 + kx], wv, a01);
                a10 = fmaf(patch[1 + ky][0 + kx], wv, a10);
                a11 = fmaf(patch[1 + ky][1 + kx], wv, a11);
            }
    }
    float bv = bl[o];
    float m = fmaxf(fmaxf(a00, a01), fmaxf(a10, a11)) + bv;
    out[idx] = fmaxf(m, 0.f);
}

// Routing stage 1: one block per batch element.
// x[r][c] = h3[b, c, r]  (R=64 spatial, C=32 channels)
// u[n][r][o] = sum_c x[r][c] * W[n][r][c][o];  3 routing iterations in LDS.
__global__ __launch_bounds__(256)
void routing1(const float* __restrict__ h3, const float* __restrict__ W,
              float* __restrict__ v1)
{
    constexpr int N = 32, R = 64, C = 32, O = 8;
    __shared__ float u[N * R * O];    // 64 KB
    __shared__ float xc[R * C];       // x first, then c_ij (N*R == R*C == 2048)
    __shared__ float bij[N * R];      // 8 KB
    __shared__ float vv[N * O];       // 1 KB

    int t = threadIdx.x;
    int b = blockIdx.x;

    // load feats (transposed view of h3)
    for (int i = t; i < R * C; i += 256) {
        int r = i / C, c = i % C;
        xc[i] = h3[(size_t)b * (C * R) + c * R + r];
    }
    for (int i = t; i < N * R; i += 256) bij[i] = 0.f;
    __syncthreads();

    // u_hat
    for (int i = t; i < N * R * O; i += 256) {
        int o = i % O;
        int r = (i / O) % R;
        int n = i / (O * R);
        const float* wp = W + ((size_t)(n * R + r) * C) * O + o;
        const float* xp = xc + r * C;
        float s = 0.f;
#pragma unroll 8
        for (int c = 0; c < C; ++c) s = fmaf(xp[c], wp[c * O], s);
        u[i] = s;
    }
    __syncthreads();

    for (int it = 0; it < 3; ++it) {
        // softmax over r per n: 32 rows x 8 lanes, each lane handles 8 r's
        {
            int n = t >> 3, j = t & 7;
            float mx = -1e30f;
            for (int k = 0; k < 8; ++k) mx = fmaxf(mx, bij[n * R + j * 8 + k]);
            for (int w = 1; w < 8; w <<= 1) mx = fmaxf(mx, __shfl_xor(mx, w, 64));
            float sum = 0.f;
            for (int k = 0; k < 8; ++k) {
                float e = expf(bij[n * R + j * 8 + k] - mx);
                xc[n * R + j * 8 + k] = e;
                sum += e;
            }
            for (int w = 1; w < 8; w <<= 1) sum += __shfl_xor(sum, w, 64);
            float inv = 1.f / sum;
            for (int k = 0; k < 8; ++k) xc[n * R + j * 8 + k] *= inv;
        }
        __syncthreads();
        // s_j and squash: 256 threads = (n, o)
        {
            int n = t >> 3, o = t & 7;
            float s = 0.f;
            for (int r = 0; r < R; ++r)
                s = fmaf(xc[n * R + r], u[(n * R + r) * O + o], s);
            float nr = s * s;
            for (int w = 1; w < 8; w <<= 1) nr += __shfl_xor(nr, w, 64);
            float scale = nr / (1.f + nr) / sqrtf(nr + 1e-9f);
            vv[t] = scale * s;
        }
        __syncthreads();
        if (it < 2) {
            for (int i = t; i < N * R; i += 256) {
                int n = i / R, r = i % R;
                const float* up = u + (n * R + r) * O;
                const float* vp = vv + n * O;
                float s = 0.f;
#pragma unroll
                for (int o = 0; o < O; ++o) s = fmaf(up[o], vp[o], s);
                bij[i] += s;
            }
            __syncthreads();
        }
    }
    v1[(size_t)b * (N * O) + t] = vv[t];  // t == n*8+o
}

// Routing stage 2 + final FC. One block per batch element.
__global__ __launch_bounds__(256)
void routing2_fc(const float* __restrict__ v1, const float* __restrict__ W,
                 const float* __restrict__ fcw, const float* __restrict__ fcb,
                 float* __restrict__ out)
{
    constexpr int N = 15, R = 32, C = 8, O = 16;
    __shared__ float u[N * R * O];   // 30 KB
    __shared__ float xl[R * C];      // 256 floats
    __shared__ float bij[N * R];     // 480
    __shared__ float cij[N * R];     // 480
    __shared__ float vv[N * O];      // 240

    int t = threadIdx.x;
    int b = blockIdx.x;

    for (int i = t; i < R * C; i += 256) xl[i] = v1[(size_t)b * (R * C) + i];
    for (int i = t; i < N * R; i += 256) bij[i] = 0.f;
    __syncthreads();

    for (int i = t; i < N * R * O; i += 256) {
        int o = i % O;
        int r = (i / O) % R;
        int n = i / (O * R);
        const float* wp = W + ((size_t)(n * R + r) * C) * O + o;
        const float* xp = xl + r * C;
        float s = 0.f;
#pragma unroll
        for (int c = 0; c < C; ++c) s = fmaf(xp[c], wp[c * O], s);
        u[i] = s;
    }
    __syncthreads();

    for (int it = 0; it < 3; ++it) {
        if (t < 240) {                      // 15 rows x 16 lanes, 2 r's per lane
            int n = t >> 4, j = t & 15;
            float b0 = bij[n * R + j * 2], b1 = bij[n * R + j * 2 + 1];
            float mx = fmaxf(b0, b1);
            for (int w = 1; w < 16; w <<= 1) mx = fmaxf(mx, __shfl_xor(mx, w, 64));
            float e0 = expf(b0 - mx), e1 = expf(b1 - mx);
            float sum = e0 + e1;
            for (int w = 1; w < 16; w <<= 1) sum += __shfl_xor(sum, w, 64);
            float inv = 1.f / sum;
            cij[n * R + j * 2] = e0 * inv;
            cij[n * R + j * 2 + 1] = e1 * inv;
        }
        __syncthreads();
        if (t < 240) {                      // (n, o)
            int n = t >> 4, o = t & 15;
            float s = 0.f;
            for (int r = 0; r < R; ++r)
                s = fmaf(cij[n * R + r], u[(n * R + r) * O + o], s);
            float nr = s * s;
            for (int w = 1; w < 16; w <<= 1) nr += __shfl_xor(nr, w, 64);
            float scale = nr / (1.f + nr) / sqrtf(nr + 1e-9f);
            vv[t] = scale * s;
        }
        __syncthreads();
        if (it < 2) {
            for (int i = t; i < N * R; i += 256) {
                int n = i / R, r = i % R;
                const float* up = u + (n * R + r) * O;
                const float* vp = vv + n * O;
                float s = 0.f;
#pragma unroll
                for (int o = 0; o < O; ++o) s = fmaf(up[o], vp[o], s);
                bij[i] += s;
            }
            __syncthreads();
        }
    }
    // FC: out[b][j] = fcb[j] + sum_k vv[k] * fcw[j*240+k]
    if (t < 15) {
        float s = fcb[t];
        for (int k = 0; k < 240; ++k) s = fmaf(vv[k], fcw[t * 240 + k], s);
        out[(size_t)b * 15 + t] = s;
    }
}

extern "C" void kernel_launch(void* const* d_in, const int* in_sizes, int n_in,
                              void* d_out, int out_size, void* d_ws, size_t ws_size,
                              hipStream_t stream) {
    const float* x    = (const float*)d_in[0];
    const float* w1   = (const float*)d_in[1];
    const float* b1   = (const float*)d_in[2];
    const float* w2   = (const float*)d_in[3];
    const float* b2   = (const float*)d_in[4];
    const float* w3   = (const float*)d_in[5];
    const float* b3   = (const float*)d_in[6];
    const float* rw1  = (const float*)d_in[7];
    const float* rw2  = (const float*)d_in[8];
    const float* fcw  = (const float*)d_in[9];
    const float* fcb  = (const float*)d_in[10];
    float* out = (float*)d_out;

    const int B = 512;
    float* ws = (float*)d_ws;
    float* h1 = ws;                                  // [512,8,32,32]  = 4,194,304
    float* h2 = h1 + (size_t)B * 8 * 32 * 32;        // [512,16,16,16] = 2,097,152
    float* h3 = h2 + (size_t)B * 16 * 16 * 16;       // [512,32,8,8]   = 1,048,576
    float* v1 = h3 + (size_t)B * 32 * 8 * 8;         // [512,32,8]     =   131,072

    {
        int total = B * 8 * 32 * 32;
        conv_relu_pool<3, 8, 64><<<(total + 255) / 256, 256, 0, stream>>>(x, w1, b1, h1, B);
    }
    {
        int total = B * 16 * 16 * 16;
        conv_relu_pool<8, 16, 32><<<(total + 255) / 256, 256, 0, stream>>>(h1, w2, b2, h2, B);
    }
    {
        int total = B * 32 * 8 * 8;
        conv_relu_pool<16, 32, 16><<<(total + 255) / 256, 256, 0, stream>>>(h2, w3, b3, h3, B);
    }
    routing1<<<B, 256, 0, stream>>>(h3, rw1, v1);
    routing2_fc<<<B, 256, 0, stream>>>(v1, rw2, fcw, fcb, out);
}

// Round 2
// 251.974 us; speedup vs baseline: 2.6395x; 2.6395x over previous
//
#include <hip/hip_runtime.h>
#include <hip/hip_bf16.h>

// ---------------------------------------------------------------------------
// CapsNet forward, fp32. B=512.
// conv kernels: one block per batch element, input staged zero-padded in LDS,
// weights transposed [c][k][o] in LDS, each thread computes NO output chans
// for an 8-wide x 2-row pre-pool strip (fused ReLU + 2x2 maxpool).
// ---------------------------------------------------------------------------

template<int CIN, int COUT, int HIN, int NO>
__global__ __launch_bounds__(256)
void conv_relu_pool(const float* __restrict__ in, const float* __restrict__ w,
                    const float* __restrict__ bias, float* __restrict__ out)
{
    constexpr int HOUT = HIN / 2;
    constexpr int PR = HIN + 2;                 // padded rows
    constexpr int PC = (HIN + 2 + 3) & ~3;      // padded row stride (words)
    constexpr int NS = HIN / 8;                 // 8-col strips (pre-pool)
    constexpr int NOP = COUT / NO;
    constexpr int NTASK = NOP * HOUT * NS;
    constexpr int XWORDS = CIN * PR * PC;
    constexpr int WWORDS = CIN * 9 * COUT;

    __shared__ float xin[CIN][PR][PC];
    __shared__ float wt[WWORDS];                // [c][k][o]
    __shared__ float bl[COUT];

    const int tid = threadIdx.x;
    const int b   = blockIdx.x;

    // zero-fill padded input (halo), stage transposed weights
    for (int i = tid; i < XWORDS; i += 256) ((float*)xin)[i] = 0.f;
    for (int i = tid; i < WWORDS; i += 256) {
        int o = i % COUT, k = (i / COUT) % 9, c = i / (COUT * 9);
        wt[i] = w[(o * CIN + c) * 9 + k];
    }
    if (tid < COUT) bl[tid] = bias[tid];
    __syncthreads();

    // stage interior: coalesced float4 global loads
    const float4* gin = (const float4*)(in + (size_t)b * CIN * HIN * HIN);
    constexpr int CHUNKS = CIN * HIN * (HIN / 4);
    for (int i = tid; i < CHUNKS; i += 256) {
        float4 v = gin[i];
        int ch = i % (HIN / 4);
        int y  = (i / (HIN / 4)) % HIN;
        int c  = i / ((HIN / 4) * HIN);
        float* dst = &xin[c][y + 1][ch * 4 + 1];
        dst[0] = v.x; dst[1] = v.y; dst[2] = v.z; dst[3] = v.w;
    }
    __syncthreads();

    for (int task = tid; task < NTASK; task += 256) {
        const int s  = task % NS;
        const int py = (task / NS) % HOUT;
        const int o0 = (task / (NS * HOUT)) * NO;
        const int X0 = s * 8;

        float acc[NO][2][8];
#pragma unroll
        for (int n = 0; n < NO; ++n)
#pragma unroll
            for (int q = 0; q < 2; ++q)
#pragma unroll
                for (int j = 0; j < 8; ++j) acc[n][q][j] = 0.f;

        for (int c = 0; c < CIN; ++c) {
            // 4 padded rows 2py..2py+3, 12 floats each (cols X0..X0+11)
            float rows[4][12];
#pragma unroll
            for (int rr = 0; rr < 4; ++rr) {
                const float4* src = (const float4*)&xin[c][2 * py + rr][X0];
#pragma unroll
                for (int j = 0; j < 3; ++j) {
                    float4 v = src[j];
                    rows[rr][j * 4 + 0] = v.x; rows[rr][j * 4 + 1] = v.y;
                    rows[rr][j * 4 + 2] = v.z; rows[rr][j * 4 + 3] = v.w;
                }
            }
            const float* wc = wt + c * 9 * COUT;
#pragma unroll
            for (int ky = 0; ky < 3; ++ky) {
#pragma unroll
                for (int n = 0; n < NO; ++n) {
                    const float w0 = wc[(ky * 3 + 0) * COUT + o0 + n];
                    const float w1 = wc[(ky * 3 + 1) * COUT + o0 + n];
                    const float w2 = wc[(ky * 3 + 2) * COUT + o0 + n];
#pragma unroll
                    for (int j = 0; j < 8; ++j) {
                        acc[n][0][j] = fmaf(rows[ky][j],     w0, acc[n][0][j]);
                        acc[n][0][j] = fmaf(rows[ky][j + 1], w1, acc[n][0][j]);
                        acc[n][0][j] = fmaf(rows[ky][j + 2], w2, acc[n][0][j]);
                        acc[n][1][j] = fmaf(rows[ky + 1][j],     w0, acc[n][1][j]);
                        acc[n][1][j] = fmaf(rows[ky + 1][j + 1], w1, acc[n][1][j]);
                        acc[n][1][j] = fmaf(rows[ky + 1][j + 2], w2, acc[n][1][j]);
                    }
                }
            }
        }
        // 2x2 maxpool + bias + relu, float4 store
#pragma unroll
        for (int n = 0; n < NO; ++n) {
            const float bv = bl[o0 + n];
            float4 ov;
            float* p = (float*)&ov;
#pragma unroll
            for (int j = 0; j < 4; ++j) {
                float m = fmaxf(fmaxf(acc[n][0][2 * j], acc[n][0][2 * j + 1]),
                                fmaxf(acc[n][1][2 * j], acc[n][1][2 * j + 1]));
                p[j] = fmaxf(m + bv, 0.f);
            }
            float* po = out + (((size_t)b * COUT + o0 + n) * HOUT + py) * HOUT + s * 4;
            *(float4*)po = ov;
        }
    }
}

// Routing stage 1: one block per batch element. float4 W loads; padded LDS
// strides to avoid bank conflicts (xc:33, u per-n:516, cij per-n:65).
__global__ __launch_bounds__(256)
void routing1(const float* __restrict__ h3, const float* __restrict__ W,
              float* __restrict__ v1)
{
    constexpr int N = 32, R = 64, C = 32, O = 8;
    constexpr int XS = 33;
    constexpr int US = 516;
    constexpr int CS = 65;
    __shared__ float u[N * US];      // ~64.5 KB
    __shared__ float xc[R * XS];
    __shared__ float cij[N * CS];
    __shared__ float bij[N * R];
    __shared__ float vv[N * O];

    int t = threadIdx.x;
    int b = blockIdx.x;

    for (int i = t; i < R * C; i += 256) {
        int r = i / C, c = i % C;
        xc[r * XS + c] = h3[(size_t)b * (C * R) + c * R + r];
    }
    for (int i = t; i < N * R; i += 256) bij[i] = 0.f;
    __syncthreads();

    // u_hat: i -> (n, r, o-half); float4 over o
    for (int i = t; i < N * R * 2; i += 256) {
        int oh = i & 1;
        int r  = (i >> 1) & (R - 1);
        int n  = i >> 7;
        const float* wb = W + ((size_t)(n * R + r) * C) * O + oh * 4;
        const float* xp = xc + r * XS;
        float4 s = make_float4(0.f, 0.f, 0.f, 0.f);
#pragma unroll 8
        for (int c = 0; c < C; ++c) {
            float xv = xp[c];
            float4 wv = *(const float4*)(wb + c * O);
            s.x = fmaf(xv, wv.x, s.x);
            s.y = fmaf(xv, wv.y, s.y);
            s.z = fmaf(xv, wv.z, s.z);
            s.w = fmaf(xv, wv.w, s.w);
        }
        *(float4*)&u[n * US + r * 8 + oh * 4] = s;
    }
    __syncthreads();

    for (int it = 0; it < 3; ++it) {
        {   // softmax over r per n: 32 n-rows x 8 lanes, 8 r's per lane
            int n = t >> 3, j = t & 7;
            float mx = -1e30f;
            for (int k = 0; k < 8; ++k) mx = fmaxf(mx, bij[n * R + j * 8 + k]);
            for (int w = 1; w < 8; w <<= 1) mx = fmaxf(mx, __shfl_xor(mx, w, 64));
            float sum = 0.f;
            float e[8];
            for (int k = 0; k < 8; ++k) {
                e[k] = expf(bij[n * R + j * 8 + k] - mx);
                sum += e[k];
            }
            for (int w = 1; w < 8; w <<= 1) sum += __shfl_xor(sum, w, 64);
            float inv = 1.f / sum;
            for (int k = 0; k < 8; ++k) cij[n * CS + j * 8 + k] = e[k] * inv;
        }
        __syncthreads();
        {   // s_j + squash: (n, o)
            int n = t >> 3, o = t & 7;
            float s = 0.f;
            for (int r = 0; r < R; ++r)
                s = fmaf(cij[n * CS + r], u[n * US + r * 8 + o], s);
            float nr = s * s;
            for (int w = 1; w < 8; w <<= 1) nr += __shfl_xor(nr, w, 64);
            float scale = nr / (1.f + nr) / sqrtf(nr + 1e-9f);
            vv[t] = scale * s;
        }
        __syncthreads();
        if (it < 2) {
            for (int i = t; i < N * R; i += 256) {
                int n = i >> 6, r = i & (R - 1);
                const float* up = u + n * US + r * 8;
                const float* vp = vv + n * O;
                float s = 0.f;
#pragma unroll
                for (int o = 0; o < O; ++o) s = fmaf(up[o], vp[o], s);
                bij[i] += s;
            }
            __syncthreads();
        }
    }
    v1[(size_t)b * (N * O) + t] = vv[t];
}

// Routing stage 2 + final FC. One block per batch element.
__global__ __launch_bounds__(256)
void routing2_fc(const float* __restrict__ v1, const float* __restrict__ W,
                 const float* __restrict__ fcw, const float* __restrict__ fcb,
                 float* __restrict__ out)
{
    constexpr int N = 15, R = 32, C = 8, O = 16;
    __shared__ float u[N * R * O];   // 30 KB
    __shared__ float xl[R * C];
    __shared__ float bij[N * R];
    __shared__ float cij[N * R];
    __shared__ float vv[N * O];

    int t = threadIdx.x;
    int b = blockIdx.x;

    for (int i = t; i < R * C; i += 256) xl[i] = v1[(size_t)b * (R * C) + i];
    for (int i = t; i < N * R; i += 256) bij[i] = 0.f;
    __syncthreads();

    for (int i = t; i < N * R * O; i += 256) {
        int o = i % O;
        int r = (i / O) % R;
        int n = i / (O * R);
        const float* wp = W + ((size_t)(n * R + r) * C) * O + o;
        const float* xp = xl + r * C;
        float s = 0.f;
#pragma unroll
        for (int c = 0; c < C; ++c) s = fmaf(xp[c], wp[c * O], s);
        u[i] = s;
    }
    __syncthreads();

    for (int it = 0; it < 3; ++it) {
        if (t < 240) {
            int n = t >> 4, j = t & 15;
            float b0 = bij[n * R + j * 2], b1 = bij[n * R + j * 2 + 1];
            float mx = fmaxf(b0, b1);
            for (int w = 1; w < 16; w <<= 1) mx = fmaxf(mx, __shfl_xor(mx, w, 64));
            float e0 = expf(b0 - mx), e1 = expf(b1 - mx);
            float sum = e0 + e1;
            for (int w = 1; w < 16; w <<= 1) sum += __shfl_xor(sum, w, 64);
            float inv = 1.f / sum;
            cij[n * R + j * 2] = e0 * inv;
            cij[n * R + j * 2 + 1] = e1 * inv;
        }
        __syncthreads();
        if (t < 240) {
            int n = t >> 4, o = t & 15;
            float s = 0.f;
            for (int r = 0; r < R; ++r)
                s = fmaf(cij[n * R + r], u[(n * R + r) * O + o], s);
            float nr = s * s;
            for (int w = 1; w < 16; w <<= 1) nr += __shfl_xor(nr, w, 64);
            float scale = nr / (1.f + nr) / sqrtf(nr + 1e-9f);
            vv[t] = scale * s;
        }
        __syncthreads();
        if (it < 2) {
            for (int i = t; i < N * R; i += 256) {
                int n = i / R, r = i % R;
                const float* up = u + (n * R + r) * O;
                const float* vp = vv + n * O;
                float s = 0.f;
#pragma unroll
                for (int o = 0; o < O; ++o) s = fmaf(up[o], vp[o], s);
                bij[i] += s;
            }
            __syncthreads();
        }
    }
    if (t < 15) {
        float s = fcb[t];
        for (int k = 0; k < 240; ++k) s = fmaf(vv[k], fcw[t * 240 + k], s);
        out[(size_t)b * 15 + t] = s;
    }
}

extern "C" void kernel_launch(void* const* d_in, const int* in_sizes, int n_in,
                              void* d_out, int out_size, void* d_ws, size_t ws_size,
                              hipStream_t stream) {
    const float* x    = (const float*)d_in[0];
    const float* w1   = (const float*)d_in[1];
    const float* b1   = (const float*)d_in[2];
    const float* w2   = (const float*)d_in[3];
    const float* b2   = (const float*)d_in[4];
    const float* w3   = (const float*)d_in[5];
    const float* b3   = (const float*)d_in[6];
    const float* rw1  = (const float*)d_in[7];
    const float* rw2  = (const float*)d_in[8];
    const float* fcw  = (const float*)d_in[9];
    const float* fcb  = (const float*)d_in[10];
    float* out = (float*)d_out;

    const int B = 512;
    float* ws = (float*)d_ws;
    float* h1 = ws;                                  // [512,8,32,32]
    float* h2 = h1 + (size_t)B * 8 * 32 * 32;        // [512,16,16,16]
    float* h3 = h2 + (size_t)B * 16 * 16 * 16;       // [512,32,8,8]
    float* v1 = h3 + (size_t)B * 32 * 8 * 8;         // [512,32,8]

    conv_relu_pool<3, 8, 64, 4><<<B, 256, 0, stream>>>(x, w1, b1, h1);
    conv_relu_pool<8, 16, 32, 4><<<B, 256, 0, stream>>>(h1, w2, b2, h2);
    conv_relu_pool<16, 32, 16, 2><<<B, 256, 0, stream>>>(h2, w3, b3, h3);
    routing1<<<B, 256, 0, stream>>>(h3, rw1, v1);
    routing2_fc<<<B, 256, 0, stream>>>(v1, rw2, fcw, fcb, out);
}

// Round 3
// 226.413 us; speedup vs baseline: 2.9374x; 1.1129x over previous
//
#include <hip/hip_runtime.h>
#include <hip/hip_bf16.h>

// ---------------------------------------------------------------------------
// CapsNet forward, fp32. B=512.
// convs: one block per batch elem, padded input in LDS, fused relu+pool.
// routing1: register-resident, lane==route, wave butterflies for softmax/s_j;
//           W pre-transposed to [n][c][r][o] (into dead h2 scratch).
// ---------------------------------------------------------------------------

template<int CIN, int COUT, int HIN, int NO>
__global__ __launch_bounds__(256)
void conv_relu_pool(const float* __restrict__ in, const float* __restrict__ w,
                    const float* __restrict__ bias, float* __restrict__ out)
{
    constexpr int HOUT = HIN / 2;
    constexpr int PR = HIN + 2;
    constexpr int PC = (HIN + 2 + 3) & ~3;
    constexpr int NS = HIN / 8;
    constexpr int NOP = COUT / NO;
    constexpr int NTASK = NOP * HOUT * NS;
    constexpr int XWORDS = CIN * PR * PC;
    constexpr int WWORDS = CIN * 9 * COUT;

    __shared__ float xin[CIN][PR][PC];
    __shared__ float wt[WWORDS];                // [c][k][o]
    __shared__ float bl[COUT];

    const int tid = threadIdx.x;
    const int b   = blockIdx.x;

    for (int i = tid; i < XWORDS; i += 256) ((float*)xin)[i] = 0.f;
    for (int i = tid; i < WWORDS; i += 256) {
        int o = i % COUT, k = (i / COUT) % 9, c = i / (COUT * 9);
        wt[i] = w[(o * CIN + c) * 9 + k];
    }
    if (tid < COUT) bl[tid] = bias[tid];
    __syncthreads();

    const float4* gin = (const float4*)(in + (size_t)b * CIN * HIN * HIN);
    constexpr int CHUNKS = CIN * HIN * (HIN / 4);
    for (int i = tid; i < CHUNKS; i += 256) {
        float4 v = gin[i];
        int ch = i % (HIN / 4);
        int y  = (i / (HIN / 4)) % HIN;
        int c  = i / ((HIN / 4) * HIN);
        float* dst = &xin[c][y + 1][ch * 4 + 1];
        dst[0] = v.x; dst[1] = v.y; dst[2] = v.z; dst[3] = v.w;
    }
    __syncthreads();

    for (int task = tid; task < NTASK; task += 256) {
        const int s  = task % NS;
        const int py = (task / NS) % HOUT;
        const int o0 = (task / (NS * HOUT)) * NO;
        const int X0 = s * 8;

        float acc[NO][2][8];
#pragma unroll
        for (int n = 0; n < NO; ++n)
#pragma unroll
            for (int q = 0; q < 2; ++q)
#pragma unroll
                for (int j = 0; j < 8; ++j) acc[n][q][j] = 0.f;

        for (int c = 0; c < CIN; ++c) {
            float rows[4][12];
#pragma unroll
            for (int rr = 0; rr < 4; ++rr) {
                const float4* src = (const float4*)&xin[c][2 * py + rr][X0];
#pragma unroll
                for (int j = 0; j < 3; ++j) {
                    float4 v = src[j];
                    rows[rr][j * 4 + 0] = v.x; rows[rr][j * 4 + 1] = v.y;
                    rows[rr][j * 4 + 2] = v.z; rows[rr][j * 4 + 3] = v.w;
                }
            }
            const float* wc = wt + c * 9 * COUT;
#pragma unroll
            for (int ky = 0; ky < 3; ++ky) {
#pragma unroll
                for (int n = 0; n < NO; ++n) {
                    const float w0 = wc[(ky * 3 + 0) * COUT + o0 + n];
                    const float w1 = wc[(ky * 3 + 1) * COUT + o0 + n];
                    const float w2 = wc[(ky * 3 + 2) * COUT + o0 + n];
#pragma unroll
                    for (int j = 0; j < 8; ++j) {
                        acc[n][0][j] = fmaf(rows[ky][j],     w0, acc[n][0][j]);
                        acc[n][0][j] = fmaf(rows[ky][j + 1], w1, acc[n][0][j]);
                        acc[n][0][j] = fmaf(rows[ky][j + 2], w2, acc[n][0][j]);
                        acc[n][1][j] = fmaf(rows[ky + 1][j],     w0, acc[n][1][j]);
                        acc[n][1][j] = fmaf(rows[ky + 1][j + 1], w1, acc[n][1][j]);
                        acc[n][1][j] = fmaf(rows[ky + 1][j + 2], w2, acc[n][1][j]);
                    }
                }
            }
        }
#pragma unroll
        for (int n = 0; n < NO; ++n) {
            const float bv = bl[o0 + n];
            float4 ov;
            float* p = (float*)&ov;
#pragma unroll
            for (int j = 0; j < 4; ++j) {
                float m = fmaxf(fmaxf(acc[n][0][2 * j], acc[n][0][2 * j + 1]),
                                fmaxf(acc[n][1][2 * j], acc[n][1][2 * j + 1]));
                p[j] = fmaxf(m + bv, 0.f);
            }
            float* po = out + (((size_t)b * COUT + o0 + n) * HOUT + py) * HOUT + s * 4;
            *(float4*)po = ov;
        }
    }
}

// W[n][r][c][o] -> Wt[n][c][r][o]  (n=32, r=64, c=32, o=8), float4 granules.
__global__ __launch_bounds__(256)
void transpose_w1(const float* __restrict__ W, float* __restrict__ Wt)
{
    int idx = blockIdx.x * 256 + threadIdx.x;   // over 32*32*64*2 dst float4s
    if (idx >= 32 * 32 * 64 * 2) return;
    int half = idx & 1;
    int r    = (idx >> 1) & 63;
    int c    = (idx >> 7) & 31;
    int n    = idx >> 12;
    ((float4*)Wt)[idx] =
        ((const float4*)W)[(((n * 64 + r) * 32 + c) << 1) + half];
}

// Routing stage 1, register-resident. lane == r (64 routes = wavefront).
// Each wave owns one n; block = 4 waves (4 n's) x G=4 batch elems.
__global__ __launch_bounds__(256)
void routing1_reg(const float* __restrict__ h3, const float* __restrict__ Wt,
                  float* __restrict__ v1)
{
    constexpr int C = 32, R = 64, O = 8, G = 4;
    const int lane = threadIdx.x & 63;
    const int n    = blockIdx.y * 4 + (threadIdx.x >> 6);
    const int b0   = blockIdx.x * G;

    float u[G][O];
#pragma unroll
    for (int g = 0; g < G; ++g)
#pragma unroll
        for (int o = 0; o < O; ++o) u[g][o] = 0.f;

    const float4* wp = (const float4*)Wt + (size_t)n * C * R * 2;
    const float* xb = h3 + (size_t)b0 * (C * R) + lane;

#pragma unroll 4
    for (int c = 0; c < C; ++c) {
        float xv[G];
#pragma unroll
        for (int g = 0; g < G; ++g) xv[g] = xb[(size_t)g * (C * R) + c * R];
        float4 w0 = wp[(c * R + lane) * 2];
        float4 w1 = wp[(c * R + lane) * 2 + 1];
#pragma unroll
        for (int g = 0; g < G; ++g) {
            u[g][0] = fmaf(xv[g], w0.x, u[g][0]);
            u[g][1] = fmaf(xv[g], w0.y, u[g][1]);
            u[g][2] = fmaf(xv[g], w0.z, u[g][2]);
            u[g][3] = fmaf(xv[g], w0.w, u[g][3]);
            u[g][4] = fmaf(xv[g], w1.x, u[g][4]);
            u[g][5] = fmaf(xv[g], w1.y, u[g][5]);
            u[g][6] = fmaf(xv[g], w1.z, u[g][6]);
            u[g][7] = fmaf(xv[g], w1.w, u[g][7]);
        }
    }

    float bij[G];
#pragma unroll
    for (int g = 0; g < G; ++g) bij[g] = 0.f;
    float v[G][O];

    for (int it = 0; it < 3; ++it) {
        // softmax over r (wave butterfly), per g
        float cc[G];
#pragma unroll
        for (int g = 0; g < G; ++g) {
            float mx = bij[g];
#pragma unroll
            for (int w = 1; w < 64; w <<= 1) mx = fmaxf(mx, __shfl_xor(mx, w, 64));
            float e = __expf(bij[g] - mx);
            float sum = e;
#pragma unroll
            for (int w = 1; w < 64; w <<= 1) sum += __shfl_xor(sum, w, 64);
            cc[g] = e / sum;
        }
        // s_j = sum_r c*u  (butterfly over lanes, all lanes end with full sum)
        float s[G][O];
#pragma unroll
        for (int g = 0; g < G; ++g)
#pragma unroll
            for (int o = 0; o < O; ++o) s[g][o] = cc[g] * u[g][o];
#pragma unroll
        for (int w = 1; w < 64; w <<= 1)
#pragma unroll
            for (int g = 0; g < G; ++g)
#pragma unroll
                for (int o = 0; o < O; ++o) s[g][o] += __shfl_xor(s[g][o], w, 64);
        // squash
#pragma unroll
        for (int g = 0; g < G; ++g) {
            float nr = 0.f;
#pragma unroll
            for (int o = 0; o < O; ++o) nr = fmaf(s[g][o], s[g][o], nr);
            float scale = nr / (1.f + nr) / sqrtf(nr + 1e-9f);
#pragma unroll
            for (int o = 0; o < O; ++o) v[g][o] = scale * s[g][o];
        }
        if (it < 2) {
#pragma unroll
            for (int g = 0; g < G; ++g) {
                float d = 0.f;
#pragma unroll
                for (int o = 0; o < O; ++o) d = fmaf(u[g][o], v[g][o], d);
                bij[g] += d;
            }
        }
    }
    if (lane < G * O) {
        int g = lane >> 3, o = lane & 7;
        v1[(size_t)(b0 + g) * 256 + n * 8 + o] = v[g][o];
    }
}

// Routing stage 2 + final FC. One block per batch element.
__global__ __launch_bounds__(256)
void routing2_fc(const float* __restrict__ v1, const float* __restrict__ W,
                 const float* __restrict__ fcw, const float* __restrict__ fcb,
                 float* __restrict__ out)
{
    constexpr int N = 15, R = 32, C = 8, O = 16;
    __shared__ float u[N * R * O];
    __shared__ float xl[R * C];
    __shared__ float bij[N * R];
    __shared__ float cij[N * R];
    __shared__ float vv[N * O];

    int t = threadIdx.x;
    int b = blockIdx.x;

    for (int i = t; i < R * C; i += 256) xl[i] = v1[(size_t)b * (R * C) + i];
    for (int i = t; i < N * R; i += 256) bij[i] = 0.f;
    __syncthreads();

    for (int i = t; i < N * R * O; i += 256) {
        int o = i % O;
        int r = (i / O) % R;
        int n = i / (O * R);
        const float* wp = W + ((size_t)(n * R + r) * C) * O + o;
        const float* xp = xl + r * C;
        float s = 0.f;
#pragma unroll
        for (int c = 0; c < C; ++c) s = fmaf(xp[c], wp[c * O], s);
        u[i] = s;
    }
    __syncthreads();

    for (int it = 0; it < 3; ++it) {
        if (t < 240) {
            int n = t >> 4, j = t & 15;
            float b0 = bij[n * R + j * 2], b1 = bij[n * R + j * 2 + 1];
            float mx = fmaxf(b0, b1);
            for (int w = 1; w < 16; w <<= 1) mx = fmaxf(mx, __shfl_xor(mx, w, 64));
            float e0 = __expf(b0 - mx), e1 = __expf(b1 - mx);
            float sum = e0 + e1;
            for (int w = 1; w < 16; w <<= 1) sum += __shfl_xor(sum, w, 64);
            float inv = 1.f / sum;
            cij[n * R + j * 2] = e0 * inv;
            cij[n * R + j * 2 + 1] = e1 * inv;
        }
        __syncthreads();
        if (t < 240) {
            int n = t >> 4, o = t & 15;
            float s = 0.f;
            for (int r = 0; r < R; ++r)
                s = fmaf(cij[n * R + r], u[(n * R + r) * O + o], s);
            float nr = s * s;
            for (int w = 1; w < 16; w <<= 1) nr += __shfl_xor(nr, w, 64);
            float scale = nr / (1.f + nr) / sqrtf(nr + 1e-9f);
            vv[t] = scale * s;
        }
        __syncthreads();
        if (it < 2) {
            for (int i = t; i < N * R; i += 256) {
                int n = i / R, r = i % R;
                const float* up = u + (n * R + r) * O;
                const float* vp = vv + n * O;
                float s = 0.f;
#pragma unroll
                for (int o = 0; o < O; ++o) s = fmaf(up[o], vp[o], s);
                bij[i] += s;
            }
            __syncthreads();
        }
    }
    if (t < 15) {
        float s = fcb[t];
        for (int k = 0; k < 240; ++k) s = fmaf(vv[k], fcw[t * 240 + k], s);
        out[(size_t)b * 15 + t] = s;
    }
}

extern "C" void kernel_launch(void* const* d_in, const int* in_sizes, int n_in,
                              void* d_out, int out_size, void* d_ws, size_t ws_size,
                              hipStream_t stream) {
    const float* x    = (const float*)d_in[0];
    const float* w1   = (const float*)d_in[1];
    const float* b1   = (const float*)d_in[2];
    const float* w2   = (const float*)d_in[3];
    const float* b2   = (const float*)d_in[4];
    const float* w3   = (const float*)d_in[5];
    const float* b3   = (const float*)d_in[6];
    const float* rw1  = (const float*)d_in[7];
    const float* rw2  = (const float*)d_in[8];
    const float* fcw  = (const float*)d_in[9];
    const float* fcb  = (const float*)d_in[10];
    float* out = (float*)d_out;

    const int B = 512;
    float* ws = (float*)d_ws;
    float* h1 = ws;                                  // [512,8,32,32]
    float* h2 = h1 + (size_t)B * 8 * 32 * 32;        // [512,16,16,16] (dead after conv3)
    float* h3 = h2 + (size_t)B * 16 * 16 * 16;       // [512,32,8,8]
    float* v1 = h3 + (size_t)B * 32 * 8 * 8;         // [512,32,8]
    float* Wt = h2;                                  // rw1 transposed, reuses h2

    conv_relu_pool<3, 8, 64, 4><<<B, 256, 0, stream>>>(x, w1, b1, h1);
    conv_relu_pool<8, 16, 32, 4><<<B, 256, 0, stream>>>(h1, w2, b2, h2);
    conv_relu_pool<16, 32, 16, 2><<<B, 256, 0, stream>>>(h2, w3, b3, h3);
    transpose_w1<<<(32 * 32 * 64 * 2 + 255) / 256, 256, 0, stream>>>(rw1, Wt);
    {
        dim3 grid(B / 4, 8);   // 128 b-groups x (32 n / 4 per block)
        routing1_reg<<<grid, 256, 0, stream>>>(h3, Wt, v1);
    }
    routing2_fc<<<B, 256, 0, stream>>>(v1, rw2, fcw, fcb, out);
}